// Round 4
// baseline (1186.553 us; speedup 1.0000x reference)
//
#include <hip/hip_runtime.h>
#include <hip/hip_bf16.h>
#include <math.h>

#define EMBED 768
#define QKVD 2304
#define HEADS 12
#define HD 64
#define HIDDEN 3072
#define NPATCH 196
#define SEQMAX 784
#define NB 8
#define IMGSZ 224
#define GRID 14
#define PATCH 16
#define PSTR 72
#define VROW 832

typedef __hip_bfloat16 bf16;
typedef __attribute__((ext_vector_type(8))) short short8;
typedef __attribute__((ext_vector_type(4))) float f32x4;

__device__ __forceinline__ float b2f(bf16 v) { return __bfloat162float(v); }
__device__ __forceinline__ float geluf(float x) {
    return 0.5f * x * (1.0f + erff(x * 0.70710678118654752f));
}

// async global->LDS, 16B per lane. LDS dest is wave-uniform base + lane*16.
__device__ __forceinline__ void async16(const bf16* g, bf16* l) {
    __builtin_amdgcn_global_load_lds(
        (const __attribute__((address_space(1))) unsigned int*)g,
        (__attribute__((address_space(3))) unsigned int*)l,
        16, 0, 0);
}

#define WAIT_VM0   0x0F70   // vmcnt(0)
#define WAIT_VM3   0x0F73   // vmcnt(3)
#define WAIT_VM4   0x0F74   // vmcnt(4)
#define WAIT_VM5   0x0F75   // vmcnt(5)
#define WAIT_VM6   0x0F76   // vmcnt(6)
#define WAIT_LGKM0 0xC07F   // lgkmcnt(0)

// ---------------------------------------------------------------------------
// Dtype detection (bf16 vs fp32 inputs).
// ---------------------------------------------------------------------------
__global__ __launch_bounds__(256)
void detect_kernel(const unsigned short* __restrict__ raw, int* __restrict__ flag)
{
    __shared__ int bad;
    if (threadIdx.x == 0) bad = 0;
    __syncthreads();
    for (int i = threadIdx.x; i < 8192; i += 256) {
        unsigned int u = (unsigned int)raw[i] << 16;
        float v = __uint_as_float(u);
        if (!(fabsf(v) <= 1e4f)) bad = 1;
    }
    __syncthreads();
    if (threadIdx.x == 0) *flag = bad;
}

// ---------------------------------------------------------------------------
// Fused converters.
// ---------------------------------------------------------------------------
struct CvtF32 {
    const void* src[19];
    int n[19];
    int dstOff[19];
    int blkOff[20];
};
__global__ __launch_bounds__(256)
void convert_f32_all(CvtF32 c, float* __restrict__ base, const int* __restrict__ flag)
{
    int f = *flag;
    int b = blockIdx.x;
    int i = 0;
    #pragma unroll
    for (int j = 0; j < 19; ++j) if (b >= c.blkOff[j + 1]) i = j + 1;
    int e = ((b - c.blkOff[i]) * 256 + threadIdx.x) * 4;
    if (e >= c.n[i]) return;
    float* dst = base + c.dstOff[i] + e;
    if (f) {
        *(float4*)dst = *(const float4*)((const float*)c.src[i] + e);
    } else {
        const bf16* s = (const bf16*)c.src[i] + e;
        dst[0] = b2f(s[0]); dst[1] = b2f(s[1]); dst[2] = b2f(s[2]); dst[3] = b2f(s[3]);
    }
}

struct CvtB16 {
    const void* src[5];
    int n[5];
    int dstOff[5];
    int blkOff[6];
};
__global__ __launch_bounds__(256)
void convert_b16_all(CvtB16 c, bf16* __restrict__ base, const int* __restrict__ flag)
{
    int f = *flag;
    int b = blockIdx.x;
    int i = 0;
    #pragma unroll
    for (int j = 0; j < 5; ++j) if (b >= c.blkOff[j + 1]) i = j + 1;
    int e = ((b - c.blkOff[i]) * 256 + threadIdx.x) * 4;
    if (e >= c.n[i]) return;
    bf16* dst = base + (size_t)c.dstOff[i] + e;
    if (f) {
        float4 v = *(const float4*)((const float*)c.src[i] + e);
        dst[0] = __float2bfloat16(v.x); dst[1] = __float2bfloat16(v.y);
        dst[2] = __float2bfloat16(v.z); dst[3] = __float2bfloat16(v.w);
    } else {
        *(uint2*)dst = *(const uint2*)((const bf16*)c.src[i] + e);
    }
}

// ---------------------------------------------------------------------------
// MFMA bf16 GEMM, templated M-tile (MT x 128), BK=32.
// Staging: A ring-2 (prefetch distance 1; A-tiles L2-hot) + B ring-3
// (distance 2). LDS: MT=64 -> 32 KB, MT=128 -> 40 KB.
// MT=128 (fc1/qkv, large-N): 16 MFMA per barrier window and 0.5 ds_read/MFMA.
// vmcnt schedule (queue-simulated; prologue B0,A0,B1; in-loop stageA(it+1)
// then stageB(it+2)): steady MT=64 vmcnt(5) / MT=128 vmcnt(6), tail 3/4, 0.
// Split-K (gridDim.z==2): partials to outF/outF2, bias on z==0 only,
// reduction fused into the consumer (ln_sum_f32 / posadd).
// Bijective XCD swizzle (m204). LDS col-slot XOR swizzle f(row)=(row>>1)&3
// on 16B slots, applied to GLOBAL source col + read slot (involution):
// bank-conflict-free (round-1: 5.4M -> 0).
// mode: 0 = fp32 out; 1 = fp32 out + residual; 2 = bf16 out + gelu;
//       3 = qkv head-split -> bf16 Q/K/V all [bh][t][64].
// ---------------------------------------------------------------------------
template<int MT>
__global__ __launch_bounds__(256, 4)
void mfma_gemm(const bf16* __restrict__ A, const bf16* __restrict__ W,
               const float* __restrict__ bias, const float* __restrict__ add,
               float* __restrict__ outF, float* __restrict__ outF2,
               bf16* __restrict__ outB,
               bf16* __restrict__ Qb, bf16* __restrict__ Kb, bf16* __restrict__ Vb,
               int M, int N, int K, int kpitch, int Ntok, int rowStride,
               int mode, int magic)
{
    constexpr int MI = MT / 32;            // m-frags per wave (4 or 2)
    __shared__ __align__(16) bf16 As[2][MT * 32];
    __shared__ __align__(16) bf16 Bs[3][128 * 32];
    int tid = threadIdx.x;
    int lane = tid & 63;
    int wave = tid >> 6;
    int wm = wave & 1, wn = wave >> 1;

    // bijective XCD-aware swizzle of the flat workgroup id (m204 form)
    unsigned nx = gridDim.x, ny = gridDim.y;
    unsigned nwg = nx * ny * gridDim.z;
    unsigned orig = blockIdx.x + nx * (blockIdx.y + ny * blockIdx.z);
    unsigned qq = nwg >> 3, rr = nwg & 7;
    unsigned xcd = orig & 7, idx8 = orig >> 3;
    unsigned wg = (xcd < rr ? xcd * (qq + 1) : rr * (qq + 1) + (xcd - rr) * qq) + idx8;
    int bxg = (int)(wg % nx);
    unsigned tmp = wg / nx;
    int byg = (int)(tmp % ny);
    int bzg = (int)(tmp / ny);

    int m0 = byg * MT, n0 = bxg * 128;
    int k0 = bzg * K;

    int lr = lane >> 2;
    int lc = lane & 3;
    int sc = lc ^ ((lr >> 1) & 3);         // swizzled col slot (16B units)
    int ar0 = (MT / 4) * wave + lr;
    int ma0 = m0 + ar0; if (ma0 >= M) ma0 = M - 1;
    int bx0 = (int)(((unsigned)ma0 * (unsigned)magic) >> 24);
    const bf16* aSrc0 = A + (size_t)(bx0 * rowStride + (ma0 - bx0 * Ntok)) * kpitch + k0 + sc * 8;
    const bf16* aSrc1 = nullptr;
    if constexpr (MT == 128) {
        int ma1 = m0 + ar0 + 16; if (ma1 >= M) ma1 = M - 1;
        int bx1 = (int)(((unsigned)ma1 * (unsigned)magic) >> 24);
        aSrc1 = A + (size_t)(bx1 * rowStride + (ma1 - bx1 * Ntok)) * kpitch + k0 + sc * 8;
    }
    const bf16* bSrc0 = W + (size_t)(n0 + 32 * wave + lr) * kpitch + k0 + sc * 8;
    const bf16* bSrc1 = W + (size_t)(n0 + 32 * wave + 16 + lr) * kpitch + k0 + sc * 8;

    int fr = lane & 15;
    int fq = lane >> 4;
    int sq = fq ^ ((fr >> 1) & 3);         // swizzled read slot
    int aOff = (wm * (MT / 2) + fr) * 32 + sq * 8;
    int bOff = (wn * 64 + fr) * 32 + sq * 8;

    f32x4 acc[MI][4] = {};

    auto stageA = [&](int buf) {
        async16(aSrc0, As[buf] + ((MT / 4) * wave) * 32);
        aSrc0 += 32;
        if constexpr (MT == 128) {
            async16(aSrc1, As[buf] + ((MT / 4) * wave + 16) * 32);
            aSrc1 += 32;
        }
    };
    auto stageB = [&](int buf) {
        async16(bSrc0, Bs[buf] + (32 * wave) * 32);
        async16(bSrc1, Bs[buf] + (32 * wave + 16) * 32);
        bSrc0 += 32; bSrc1 += 32;
    };

    int nIter = K >> 5;                 // >= 12 at all call sites
    // prologue issue order matters for the vmcnt counting: B(0), A(0), B(1)
    stageB(0);
    stageA(0);
    stageB(1);

    int cur = 0;                        // Bs ring index (= it % 3); As index = it & 1
    for (int it = 0; it < nIter; ++it) {
        __builtin_amdgcn_sched_barrier(0);
        __builtin_amdgcn_s_waitcnt(WAIT_LGKM0);   // my reads of overwrite targets done
        __builtin_amdgcn_s_barrier();             // all waves done reading them
        if (it + 1 < nIter) stageA((it + 1) & 1);
        if (it + 2 < nIter) {
            int nb = cur + 2; if (nb >= 3) nb -= 3;
            stageB(nb);
            // drain A(it)+B(it); leave B(it+1), A(it+1), B(it+2) in flight
            if constexpr (MT == 128) __builtin_amdgcn_s_waitcnt(WAIT_VM6);
            else                     __builtin_amdgcn_s_waitcnt(WAIT_VM5);
        } else if (it + 1 < nIter) {
            if constexpr (MT == 128) __builtin_amdgcn_s_waitcnt(WAIT_VM4);
            else                     __builtin_amdgcn_s_waitcnt(WAIT_VM3);
        } else {
            __builtin_amdgcn_s_waitcnt(WAIT_VM0);
        }
        __builtin_amdgcn_s_barrier();             // current buffers visible to all waves
        __builtin_amdgcn_sched_barrier(0);

        const bf16* aR = As[it & 1] + aOff;
        const bf16* bR = Bs[cur] + bOff;
        short8 af[MI], bfr[4];
        #pragma unroll
        for (int mi = 0; mi < MI; ++mi) af[mi] = *(const short8*)(aR + mi * 16 * 32);
        #pragma unroll
        for (int ni = 0; ni < 4; ++ni) bfr[ni] = *(const short8*)(bR + ni * 16 * 32);
        #pragma unroll
        for (int mi = 0; mi < MI; ++mi)
            #pragma unroll
            for (int ni = 0; ni < 4; ++ni)
                acc[mi][ni] = __builtin_amdgcn_mfma_f32_16x16x32_bf16(
                    af[mi], bfr[ni], acc[mi][ni], 0, 0, 0);
        if (++cur >= 3) cur = 0;
    }

    // ---- epilogue ----
    float* oF = bzg ? outF2 : outF;
    float bsv[4];
    #pragma unroll
    for (int ni = 0; ni < 4; ++ni)
        bsv[ni] = bzg ? 0.f : bias[n0 + wn * 64 + ni * 16 + fr];

    if (mode == 3) {
        bf16* dstb[4]; int hhv[4], dcv[4];
        #pragma unroll
        for (int ni = 0; ni < 4; ++ni) {
            int nb = n0 + wn * 64 + ni * 16;          // multiple of 16 -> lane-uniform
            int which = (nb >= 1536) ? 2 : (nb >= 768) ? 1 : 0;
            int nnb = nb - which * 768;
            dstb[ni] = (which == 0) ? Qb : (which == 1) ? Kb : Vb;
            hhv[ni] = nnb >> 6;
            dcv[ni] = (nnb & 63) + fr;
        }
        #pragma unroll
        for (int mi = 0; mi < MI; ++mi)
            #pragma unroll
            for (int r = 0; r < 4; ++r) {
                int m = m0 + wm * (MT / 2) + mi * 16 + fq * 4 + r;
                if (m >= M) continue;
                int bx_ = (int)(((unsigned)m * (unsigned)magic) >> 24);
                int t = m - bx_ * Ntok;
                #pragma unroll
                for (int ni = 0; ni < 4; ++ni)
                    dstb[ni][((size_t)(bx_ * HEADS + hhv[ni]) * SEQMAX + t) * HD + dcv[ni]]
                        = __float2bfloat16(acc[mi][ni][r] + bsv[ni]);
            }
    } else {
        #pragma unroll
        for (int mi = 0; mi < MI; ++mi)
            #pragma unroll
            for (int r = 0; r < 4; ++r) {
                int m = m0 + wm * (MT / 2) + mi * 16 + fq * 4 + r;
                if (m >= M) continue;
                int bx_ = (int)(((unsigned)m * (unsigned)magic) >> 24);
                int t = m - bx_ * Ntok;
                size_t rb = (size_t)(bx_ * rowStride + t) * N;
                #pragma unroll
                for (int ni = 0; ni < 4; ++ni) {
                    int n = n0 + wn * 64 + ni * 16 + fr;
                    float v = acc[mi][ni][r] + bsv[ni];
                    if (mode == 0)      oF[rb + n] = v;
                    else if (mode == 1) oF[rb + n] = v + add[rb + n];
                    else                outB[rb + n] = __float2bfloat16(geluf(v));
                }
            }
    }
}

// ---------------------------------------------------------------------------
// Legacy fp32 GEMM (tiny head matmuls only).
// ---------------------------------------------------------------------------
__global__ __launch_bounds__(256)
void gemm_kernel(const float* __restrict__ A, const float* __restrict__ W,
                 const float* __restrict__ bias, const float* __restrict__ add,
                 float* __restrict__ C, int M, int N, int K,
                 int Ntok, int rowStride, int dogelu)
{
    __shared__ __align__(16) float As[16][68];
    __shared__ __align__(16) float Ws[16][68];
    int tid = threadIdx.x;
    int tx = tid & 15, ty = tid >> 4;
    int n0 = blockIdx.x * 64, m0 = blockIdx.y * 64;
    int lrow = tid >> 2;
    int lk   = (tid & 3) << 2;
    int am = m0 + lrow;
    bool aok = (am < M);
    const float* Arow = A;
    if (aok) {
        int pr = (am / Ntok) * rowStride + (am % Ntok);
        Arow = A + (size_t)pr * K;
    }
    int wn = n0 + lrow;
    const float* Wrow = (wn < N) ? (W + (size_t)wn * K) : nullptr;
    float acc[4][4] = {};
    for (int kk = 0; kk < K; kk += 16) {
        float4 av = make_float4(0.f, 0.f, 0.f, 0.f);
        if (aok) av = *(const float4*)(Arow + kk + lk);
        float4 wv = make_float4(0.f, 0.f, 0.f, 0.f);
        if (Wrow) wv = *(const float4*)(Wrow + kk + lk);
        __syncthreads();
        As[lk+0][lrow] = av.x; As[lk+1][lrow] = av.y;
        As[lk+2][lrow] = av.z; As[lk+3][lrow] = av.w;
        Ws[lk+0][lrow] = wv.x; Ws[lk+1][lrow] = wv.y;
        Ws[lk+2][lrow] = wv.z; Ws[lk+3][lrow] = wv.w;
        __syncthreads();
        #pragma unroll
        for (int k = 0; k < 16; ++k) {
            float4 a = *(const float4*)&As[k][ty << 2];
            float4 w = *(const float4*)&Ws[k][tx << 2];
            acc[0][0] += a.x*w.x; acc[0][1] += a.x*w.y; acc[0][2] += a.x*w.z; acc[0][3] += a.x*w.w;
            acc[1][0] += a.y*w.x; acc[1][1] += a.y*w.y; acc[1][2] += a.y*w.z; acc[1][3] += a.y*w.w;
            acc[2][0] += a.z*w.x; acc[2][1] += a.z*w.y; acc[2][2] += a.z*w.z; acc[2][3] += a.z*w.w;
            acc[3][0] += a.w*w.x; acc[3][1] += a.w*w.y; acc[3][2] += a.w*w.z; acc[3][3] += a.w*w.w;
        }
    }
    #pragma unroll
    for (int i = 0; i < 4; ++i) {
        int m = m0 + (ty << 2) + i;
        if (m >= M) continue;
        int pr = (m / Ntok) * rowStride + (m % Ntok);
        float* crow = C + (size_t)pr * N;
        const float* addrow = add ? (add + (size_t)pr * N) : nullptr;
        #pragma unroll
        for (int j = 0; j < 4; ++j) {
            int n = n0 + (tx << 2) + j;
            float v = acc[i][j] + bias[n];
            if (addrow) v += addrow[n];
            if (dogelu) v = geluf(v);
            crow[n] = v;
        }
    }
}

// ---------------------------------------------------------------------------
// LayerNorms.
// ---------------------------------------------------------------------------
__global__ __launch_bounds__(256)
void ln_bf16_kernel(const float* __restrict__ src, bf16* __restrict__ dst,
                    const float* __restrict__ g, const float* __restrict__ bta, int Ntok)
{
    __shared__ float red[256];
    int blk = blockIdx.x;
    int t = blk % Ntok, b = blk / Ntok;
    size_t row = ((size_t)b * SEQMAX + t) * EMBED;
    int tid = threadIdx.x;
    float v0 = src[row + tid], v1 = src[row + tid + 256], v2 = src[row + tid + 512];
    red[tid] = v0 + v1 + v2;
    __syncthreads();
    for (int off = 128; off; off >>= 1) { if (tid < off) red[tid] += red[tid + off]; __syncthreads(); }
    float mu = red[0] * (1.0f / EMBED);
    __syncthreads();
    float d0 = v0 - mu, d1 = v1 - mu, d2 = v2 - mu;
    red[tid] = d0*d0 + d1*d1 + d2*d2;
    __syncthreads();
    for (int off = 128; off; off >>= 1) { if (tid < off) red[tid] += red[tid + off]; __syncthreads(); }
    float rs = rsqrtf(red[0] * (1.0f / EMBED) + 1e-5f);
    dst[row + tid]       = __float2bfloat16(d0 * rs * g[tid]       + bta[tid]);
    dst[row + tid + 256] = __float2bfloat16(d1 * rs * g[tid + 256] + bta[tid + 256]);
    dst[row + tid + 512] = __float2bfloat16(d2 * rs * g[tid + 512] + bta[tid + 512]);
}

__global__ __launch_bounds__(256)
void ln_kernel(const float* __restrict__ src, float* __restrict__ dst,
               const float* __restrict__ g, const float* __restrict__ bta, int Ntok)
{
    __shared__ float red[256];
    int blk = blockIdx.x;
    int t = blk % Ntok, b = blk / Ntok;
    size_t row = ((size_t)b * SEQMAX + t) * EMBED;
    int tid = threadIdx.x;
    float v0 = src[row + tid], v1 = src[row + tid + 256], v2 = src[row + tid + 512];
    red[tid] = v0 + v1 + v2;
    __syncthreads();
    for (int off = 128; off; off >>= 1) { if (tid < off) red[tid] += red[tid + off]; __syncthreads(); }
    float mu = red[0] * (1.0f / EMBED);
    __syncthreads();
    float d0 = v0 - mu, d1 = v1 - mu, d2 = v2 - mu;
    red[tid] = d0*d0 + d1*d1 + d2*d2;
    __syncthreads();
    for (int off = 128; off; off >>= 1) { if (tid < off) red[tid] += red[tid + off]; __syncthreads(); }
    float rs = rsqrtf(red[0] * (1.0f / EMBED) + 1e-5f);
    dst[row + tid]       = d0 * rs * g[tid]       + bta[tid];
    dst[row + tid + 256] = d1 * rs * g[tid + 256] + bta[tid + 256];
    dst[row + tid + 512] = d2 * rs * g[tid + 512] + bta[tid + 512];
}

// Split-K reduction fused into ln2: X = LN(pa + pb + X) (in-place residual).
__global__ __launch_bounds__(256)
void ln_sum_f32_kernel(const float* __restrict__ pa, const float* __restrict__ pb,
                       float* __restrict__ X, const float* __restrict__ g,
                       const float* __restrict__ bta, int Ntok)
{
    __shared__ float red[256];
    int blk = blockIdx.x;
    int t = blk % Ntok, b = blk / Ntok;
    size_t row = ((size_t)b * SEQMAX + t) * EMBED;
    int tid = threadIdx.x;
    float v0 = pa[row + tid]       + pb[row + tid]       + X[row + tid];
    float v1 = pa[row + tid + 256] + pb[row + tid + 256] + X[row + tid + 256];
    float v2 = pa[row + tid + 512] + pb[row + tid + 512] + X[row + tid + 512];
    red[tid] = v0 + v1 + v2;
    __syncthreads();
    for (int off = 128; off; off >>= 1) { if (tid < off) red[tid] += red[tid + off]; __syncthreads(); }
    float mu = red[0] * (1.0f / EMBED);
    __syncthreads();
    float d0 = v0 - mu, d1 = v1 - mu, d2 = v2 - mu;
    red[tid] = d0*d0 + d1*d1 + d2*d2;
    __syncthreads();
    for (int off = 128; off; off >>= 1) { if (tid < off) red[tid] += red[tid + off]; __syncthreads(); }
    float rs = rsqrtf(red[0] * (1.0f / EMBED) + 1e-5f);
    X[row + tid]       = d0 * rs * g[tid]       + bta[tid];
    X[row + tid + 256] = d1 * rs * g[tid + 256] + bta[tid + 256];
    X[row + tid + 512] = d2 * rs * g[tid + 512] + bta[tid + 512];
}

// ---------------------------------------------------------------------------
// V transpose: V [bh][t][64] -> VT [bh*64+d][VROW], zero-padded keys>=Ntok.
// XCD-pinned decode: same bh -> same XCD as flash (bh = (flat&7)*12 + j%12),
// so VT is produced into the L2 that flash will read it from.
// ---------------------------------------------------------------------------
__global__ __launch_bounds__(256)
void vtrans_kernel(const bf16* __restrict__ Vh, bf16* __restrict__ VT, int Ntok)
{
    __shared__ unsigned short Lt[64 * 66];
    unsigned o = blockIdx.x + gridDim.x * blockIdx.y;   // grid (96, nkt)
    unsigned x = o & 7, j = o >> 3;
    int bh = (int)(x * 12 + j % 12);
    int k0 = (int)(j / 12) * 64;
    const bf16* Vb = Vh + (size_t)bh * SEQMAX * HD;
    int tid = threadIdx.x;
    #pragma unroll
    for (int pass = 0; pass < 8; ++pass) {
        int key_l = (tid >> 5) + pass * 8;
        int d2 = tid & 31;
        unsigned v = 0;
        if (k0 + key_l < Ntok)
            v = *(const unsigned*)(Vb + (size_t)(k0 + key_l) * HD + d2 * 2);
        *(unsigned*)&Lt[key_l * 66 + 2 * d2] = v;
    }
    __syncthreads();
    #pragma unroll
    for (int pass = 0; pass < 8; ++pass) {
        int d = (tid >> 5) + pass * 8;
        int kp = tid & 31;
        unsigned lo = Lt[(2 * kp) * 66 + d];
        unsigned hi = Lt[(2 * kp + 1) * 66 + d];
        *(unsigned*)(VT + ((size_t)bh * HD + d) * VROW + k0 + 2 * kp) = lo | (hi << 16);
    }
}

// ---------------------------------------------------------------------------
// MFMA flash attention v5. Round-3 diagnosis: duration grid-invariant ->
// residency register-capped (~2 blocks/CU incl AGPRs) AND K/V loads were
// L2-hostile (no XCD affinity: each XCD streamed ~19MB/layer through 4MB L2
// -> ~900cyc misses on the critical chain). Fixes:
// (1) XCD-pin by bh: flat&7 selects XCD, bh = xcd*12 + j%12 -> per-XCD K/V
//     working set 12bh x 200KB = 2.4MB < 4MB L2 (vtrans pinned identically).
// (2) -32 VGPRs: softmax fused into the QK kg-loop (S consumed immediately,
//     s[2][4][4] eliminated) -> 3 waves/SIMD.
// K-prefetch now after the kg loop (hides under P roundtrip + PV).
// Key-split z=2 retained (exact combine; max-free softmax).
// ---------------------------------------------------------------------------
__global__ __launch_bounds__(256)
void flash_mfma(const bf16* __restrict__ Qh, const bf16* __restrict__ Kh,
                const bf16* __restrict__ VT, float* __restrict__ O0,
                float* __restrict__ O1, float* __restrict__ Lp, int Ntok)
{
    __shared__ __align__(16) unsigned short Plds[4][32 * PSTR];
    // XCD-pinned bijective decode of (bh, q-tile, z) from the flat id.
    // grid = (96, nqt, 2); nwg = 96*nqt*2 (multiple of 8).
    unsigned nqt = gridDim.y;
    unsigned o = blockIdx.x + gridDim.x * (blockIdx.y + nqt * blockIdx.z);
    unsigned x = o & 7, j = o >> 3;
    int bh = (int)(x * 12 + j % 12);
    unsigned rem = j / 12;                 // [0, nqt*2)
    int t0 = (int)(rem % nqt) * 128;
    int z = (int)(rem / nqt);

    int b = bh / HEADS, h = bh % HEADS;
    int tid = threadIdx.x;
    int lane = tid & 63, w = tid >> 6;
    int fr = lane & 15, fq = lane >> 4;

    int ntile = (Ntok + 63) >> 6;
    int half = (ntile + 1) >> 1;
    int kt0 = z ? half : 0;
    int kt1 = z ? ntile : half;
    float* Op = z ? O1 : O0;
    float* Lz = Lp + (size_t)z * (NB * HEADS * SEQMAX) + (size_t)bh * SEQMAX;

    const bf16* Qb = Qh + (size_t)bh * SEQMAX * HD;
    const bf16* Kb = Kh + (size_t)bh * SEQMAX * HD;
    const bf16* Vt = VT + (size_t)bh * HD * VROW;

    short8 aq[2][2];
    #pragma unroll
    for (int qi = 0; qi < 2; ++qi) {
        int tq = t0 + w * 32 + qi * 16 + fr; if (tq >= Ntok) tq = Ntok - 1;
        aq[qi][0] = *(const short8*)(Qb + (size_t)tq * HD + fq * 8);
        aq[qi][1] = *(const short8*)(Qb + (size_t)tq * HD + fq * 8 + 32);
    }

    float lpart[2][4] = {};
    f32x4 oacc[2][4];
    #pragma unroll
    for (int qi = 0; qi < 2; ++qi)
        #pragma unroll
        for (int dg = 0; dg < 4; ++dg) oacc[qi][dg] = (f32x4){0.f, 0.f, 0.f, 0.f};

    unsigned short* Pw = Plds[w];

    short8 bk[4][2];
    auto loadK = [&](int kt) {
        int kk = kt * 64;
        #pragma unroll
        for (int kg = 0; kg < 4; ++kg) {
            int key = kk + kg * 16 + fr;
            int keyc = key < Ntok ? key : Ntok - 1;
            bk[kg][0] = *(const short8*)(Kb + (size_t)keyc * HD + fq * 8);
            bk[kg][1] = *(const short8*)(Kb + (size_t)keyc * HD + fq * 8 + 32);
        }
    };
    loadK(kt0);                            // prologue: K for first tile

    for (int kt = kt0; kt < kt1; ++kt) {
        int k0 = kt * 64;
        // V loads for this tile: consumed after softmax (QK+softmax covers them)
        short8 bv[4][2];
        #pragma unroll
        for (int dg = 0; dg < 4; ++dg) {
            int d = dg * 16 + fr;
            bv[dg][0] = *(const short8*)(Vt + (size_t)d * VROW + k0 + fq * 8);
            bv[dg][1] = *(const short8*)(Vt + (size_t)d * VROW + k0 + fq * 8 + 32);
        }

        // QK + softmax fused per kg: S consumed immediately (no s[2][4][4]
        // array -> -32 VGPR -> 3 waves/SIMD residency).
        #pragma unroll
        for (int kg = 0; kg < 4; ++kg) {
            bool ok = (k0 + kg * 16 + fr) < Ntok;
            #pragma unroll
            for (int qi = 0; qi < 2; ++qi) {
                f32x4 sa = (f32x4){0.f, 0.f, 0.f, 0.f};
                sa = __builtin_amdgcn_mfma_f32_16x16x32_bf16(aq[qi][0], bk[kg][0], sa, 0, 0, 0);
                sa = __builtin_amdgcn_mfma_f32_16x16x32_bf16(aq[qi][1], bk[kg][1], sa, 0, 0, 0);
                #pragma unroll
                for (int r = 0; r < 4; ++r) {
                    float p = ok ? __expf(fminf(sa[r] * 0.125f, 80.f)) : 0.f;
                    lpart[qi][r] += p;
                    bf16 pb = __float2bfloat16(p);
                    Pw[(qi * 16 + fq * 4 + r) * PSTR + kg * 16 + fr] = *(unsigned short*)&pb;
                }
            }
        }

        // prefetch next tile's K: latency hides under P roundtrip + PV
        if (kt + 1 < kt1) loadK(kt + 1);

        short8 ap[2][2];
        #pragma unroll
        for (int qi = 0; qi < 2; ++qi) {
            ap[qi][0] = *(const short8*)(Pw + (qi * 16 + fr) * PSTR + fq * 8);
            ap[qi][1] = *(const short8*)(Pw + (qi * 16 + fr) * PSTR + fq * 8 + 32);
        }

        #pragma unroll
        for (int qi = 0; qi < 2; ++qi)
            #pragma unroll
            for (int dg = 0; dg < 4; ++dg) {
                oacc[qi][dg] = __builtin_amdgcn_mfma_f32_16x16x32_bf16(
                    ap[qi][0], bv[dg][0], oacc[qi][dg], 0, 0, 0);
                oacc[qi][dg] = __builtin_amdgcn_mfma_f32_16x16x32_bf16(
                    ap[qi][1], bv[dg][1], oacc[qi][dg], 0, 0, 0);
            }
    }

    // epilogue: unnormalized partials. Op[b,t,h*64+d] (fp32), Lz[t] = row sum.
    #pragma unroll
    for (int qi = 0; qi < 2; ++qi)
        #pragma unroll
        for (int r = 0; r < 4; ++r) {
            float l = lpart[qi][r];
            l += __shfl_xor(l, 1); l += __shfl_xor(l, 2);
            l += __shfl_xor(l, 4); l += __shfl_xor(l, 8);
            int t = t0 + w * 32 + qi * 16 + fq * 4 + r;
            if (t >= Ntok) continue;
            float* dst = Op + ((size_t)b * SEQMAX + t) * EMBED + h * HD;
            #pragma unroll
            for (int dg = 0; dg < 4; ++dg)
                dst[dg * 16 + fr] = oacc[qi][dg][r];
            if (fr == 0) Lz[t] = l;
        }
}

// Combine: Ob = (O0 + O1) / (l0 + l1), fp32 partials -> bf16.
__global__ __launch_bounds__(256)
void attn_combine(const float* __restrict__ O0, const float* __restrict__ O1,
                  const float* __restrict__ Lp, bf16* __restrict__ Ob, int Ntok)
{
    int blk = blockIdx.x;
    int t = blk % Ntok, b = blk / Ntok;
    size_t row = ((size_t)b * SEQMAX + t) * EMBED;
    int tid = threadIdx.x;
    const float* L1 = Lp + NB * HEADS * SEQMAX;
    #pragma unroll
    for (int j = 0; j < 3; ++j) {
        int e = tid + j * 256;
        int h = e >> 6;
        size_t li = ((size_t)b * HEADS + h) * SEQMAX + t;
        float inv = 1.0f / (Lp[li] + L1[li]);
        Ob[row + e] = __float2bfloat16((O0[row + e] + O1[row + e]) * inv);
    }
}

// ---------------------------------------------------------------------------
__global__ __launch_bounds__(256)
void patch_gather(const void* __restrict__ img, bf16* __restrict__ Ap,
                  const int* __restrict__ flag)
{
    int f = *flag;
    int idx = blockIdx.x * 256 + threadIdx.x;
    if (idx >= NB * NPATCH * EMBED) return;
    int col = idx % EMBED;
    int row = idx / EMBED;
    int t = row % NPATCH, b = row / NPATCH;
    int c = col >> 8;
    int pr = (col >> 4) & 15;
    int pc = col & 15;
    int gr = t / GRID, gc = t % GRID;
    size_t off = ((size_t)(b * 3 + c) * IMGSZ + gr * PATCH + pr) * IMGSZ + gc * PATCH + pc;
    float v = f ? ((const float*)img)[off] : b2f(((const bf16*)img)[off]);
    Ap[idx] = __float2bfloat16(v);
}

__global__ __launch_bounds__(256)
void posadd_kernel(const float* __restrict__ PEO, const float* __restrict__ PEO2,
                   const float* __restrict__ sp, const float* __restrict__ ip,
                   float* __restrict__ X, int imgIdx)
{
    int idx = blockIdx.x * 256 + threadIdx.x;
    if (idx >= NB * NPATCH * EMBED) return;
    int e = idx % EMBED;
    int row = idx / EMBED;
    int t = row % NPATCH, b = row / NPATCH;
    float pos = (e < 384) ? sp[t * 384 + e] : ip[imgIdx * 384 + (e - 384)];
    X[((size_t)b * SEQMAX + imgIdx * NPATCH + t) * EMBED + e] = PEO[idx] + PEO2[idx] + pos;
}

__global__ __launch_bounds__(768)
void mean_kernel(const float* __restrict__ H, float* __restrict__ Mn)
{
    int b = blockIdx.x;
    int e = threadIdx.x;
    float s = 0.f;
    for (int t = 0; t < SEQMAX; ++t) s += H[((size_t)b * SEQMAX + t) * EMBED + e];
    Mn[b * EMBED + e] = s * (1.0f / SEQMAX);
}

__global__ __launch_bounds__(256)
void bcast_kernel(const float* __restrict__ P, void* __restrict__ out,
                  const int* __restrict__ flag)
{
    int f = *flag;
    int idx = blockIdx.x * 256 + threadIdx.x;
    if (idx >= NB * IMGSZ * IMGSZ) return;
    int c = idx % IMGSZ;
    int r = (idx / IMGSZ) % IMGSZ;
    int b = idx / (IMGSZ * IMGSZ);
    float v = P[b * 256 + (r & 15) * 16 + (c & 15)];
    if (f) ((float*)out)[idx] = v;
    else   ((bf16*)out)[idx] = __float2bfloat16(v);
}

// ---------------------------------------------------------------------------
extern "C" void kernel_launch(void* const* d_in, const int* in_sizes, int n_in,
                              void* d_out, int out_size, void* d_ws, size_t ws_size,
                              hipStream_t stream)
{
    (void)n_in; (void)out_size; (void)ws_size;
    const void* img[4] = {d_in[0], d_in[1], d_in[2], d_in[3]};

    float* ws = (float*)d_ws;
    int* flag = (int*)ws;

    detect_kernel<<<1, 256, 0, stream>>>((const unsigned short*)d_in[0], flag);

    const bool isBig[28] = {0,0,0,0, 1,0,0,0, 0,0,1,0, 1,0,0,0, 1,0,1,0, 0,0,0,0, 0,0,0,0};
    float* fBase = ws + 16;
    float* fPtr[28] = {};
    CvtF32 cf;
    int fCnt = 0, fBlk = 0;
    cf.blkOff[0] = 0;
    {
        float* p = fBase;
        for (int i = 4; i < 28; ++i) {
            if (isBig[i]) continue;
            fPtr[i] = p;
            int n = in_sizes[i];
            cf.src[fCnt] = d_in[i];
            cf.n[fCnt] = n;
            cf.dstOff[fCnt] = (int)(p - fBase);
            fBlk += (n + 1023) / 1024;
            cf.blkOff[fCnt + 1] = fBlk;
            p += n;
            ++fCnt;
        }
        fBase = ws + 16;
        fPtr[0] = p;   // sentinel: arena end
    }
    convert_f32_all<<<fBlk, 256, 0, stream>>>(cf, fBase, flag);

    bf16* bPtr[28] = {};
    bf16* bBase = (bf16*)fPtr[0];
    CvtB16 cb;
    int bCnt = 0, bBlk = 0;
    cb.blkOff[0] = 0;
    float* arenaEnd;
    {
        bf16* p = bBase;
        for (int i = 4; i < 28; ++i) {
            if (!isBig[i]) continue;
            bPtr[i] = p;
            int n = in_sizes[i];
            cb.src[bCnt] = d_in[i];
            cb.n[bCnt] = n;
            cb.dstOff[bCnt] = (int)(p - bBase);
            bBlk += (n + 1023) / 1024;
            cb.blkOff[bCnt + 1] = bBlk;
            p += n;
            ++bCnt;
        }
        size_t off = p - (bf16*)ws;
        off = (off + 7) & ~(size_t)7;
        arenaEnd = (float*)((bf16*)ws + off);
    }
    convert_b16_all<<<bBlk, 256, 0, stream>>>(cb, bBase, flag);

    const bf16* pe_w   = bPtr[4];
    const bf16* qkv_w  = bPtr[10];
    const bf16* proj_w = bPtr[12];
    const bf16* fc1_w  = bPtr[16];
    const bf16* fc2_w  = bPtr[18];
    const float* pe_b      = fPtr[5];
    const float* sp        = fPtr[6];
    const float* ip        = fPtr[7];
    const float* ln_attn_g = fPtr[8];
    const float* ln_attn_b = fPtr[9];
    const float* qkv_b     = fPtr[11];
    const float* proj_b    = fPtr[13];
    const float* ln1_g     = fPtr[14];
    const float* ln1_b     = fPtr[15];
    const float* fc1_b     = fPtr[17];
    const float* fc2_b     = fPtr[19];
    const float* ln2_g     = fPtr[20];
    const float* ln2_b     = fPtr[21];
    const float* final_g   = fPtr[22];
    const float* final_b   = fPtr[23];
    const float* head_w1   = fPtr[24];
    const float* head_b1   = fPtr[25];
    const float* head_w2   = fPtr[26];
    const float* head_b2   = fPtr[27];

    const size_t SEQ = (size_t)NB * SEQMAX * EMBED;          // 4,816,896
    const size_t HID_ELEMS = (size_t)NB * SEQMAX * HIDDEN;   // 19,267,584
    const size_t EMB_ELEMS = (size_t)NB * NPATCH * EMBED;    // 1,204,224
    float* X    = arenaEnd;
    float* H    = X + SEQ;
    float* O    = H + SEQ;
    float* PEO  = O + SEQ;
    float* MEAN = PEO + EMB_ELEMS;
    float* HH   = MEAN + NB * EMBED;
    float* PTCH = HH + NB * EMBED;
    bf16* Hb    = (bf16*)(PTCH + NB * 256 + 16);
    bf16* Ob    = Hb + SEQ;
    bf16* Gb    = Ob + SEQ;
    bf16* PEb   = Gb + HID_ELEMS;
    bf16* Qb    = PEb + EMB_ELEMS;
    bf16* Kb    = Qb + SEQ;
    bf16* Vb    = Kb + SEQ;
    bf16* VTb   = Vb + SEQ;
    float* Lbuf = (float*)(VTb + (size_t)NB * HEADS * HD * VROW);  // 2 x NBH x SEQMAX

    const int nEmb = NB * NPATCH * EMBED;

    // magic for unsigned division by d via (m*magic)>>24; valid for the q<=7,
    // d in {392,588,784,1568} cases used here ((q+1)*e < magic holds).
    auto magicOf = [](int d) { return (int)(16777216u / (unsigned)d + 1u); };
    const int mgE = magicOf(NB * NPATCH);

    auto embed = [&](int i) {
        patch_gather<<<(nEmb + 255) / 256, 256, 0, stream>>>(img[i], PEb, flag);
        // split-K z=2 (grid was 150 blocks -> badly grid-starved); partials
        // PEO + H (H is free scratch at embed time), summed in posadd.
        dim3 g(EMBED / 128, (NB * NPATCH + 63) / 64, 2);
        mfma_gemm<64><<<g, 256, 0, stream>>>(PEb, pe_w + (size_t)i * EMBED * EMBED,
                                             pe_b + i * EMBED, nullptr, PEO, H, nullptr,
                                             nullptr, nullptr, nullptr,
                                             NB * NPATCH, EMBED, EMBED / 2, EMBED,
                                             NB * NPATCH, NB * NPATCH, 0, mgE);
        posadd_kernel<<<(nEmb + 255) / 256, 256, 0, stream>>>(PEO, H, sp, ip, X, i);
    };

    auto block = [&](int i, int Ntok) {
        int M = NB * Ntok;
        int gy64  = (M + 63) / 64;
        int gy128 = (M + 127) / 128;
        int nkt = (Ntok + 63) / 64;
        int nqt = (Ntok + 127) / 128;
        int mg = magicOf(Ntok);
        ln_bf16_kernel<<<M, 256, 0, stream>>>(X, Hb, ln_attn_g + i * EMBED, ln_attn_b + i * EMBED, Ntok);
        mfma_gemm<128><<<dim3(QKVD / 128, gy128), 256, 0, stream>>>(
            Hb, qkv_w + (size_t)i * QKVD * EMBED, qkv_b + i * QKVD, nullptr,
            nullptr, nullptr, nullptr, Qb, Kb, Vb, M, QKVD, EMBED, EMBED,
            Ntok, SEQMAX, 3, mg);
        vtrans_kernel<<<dim3(NB * HEADS, nkt), 256, 0, stream>>>(Vb, VTb, Ntok);
        // key-split z=2 flash: partials into O (z0) / H (z1), combine -> Ob
        flash_mfma<<<dim3(NB * HEADS, nqt, 2), 256, 0, stream>>>(
            Qb, Kb, VTb, O, H, Lbuf, Ntok);
        attn_combine<<<M, 256, 0, stream>>>(O, H, Lbuf, Ob, Ntok);
        mfma_gemm<64><<<dim3(EMBED / 128, gy64), 256, 0, stream>>>(
            Ob, proj_w + (size_t)i * EMBED * EMBED, proj_b + i * EMBED, X,
            X, nullptr, nullptr, nullptr, nullptr, nullptr,
            M, EMBED, EMBED, EMBED, Ntok, SEQMAX, 1, mg);
        ln_bf16_kernel<<<M, 256, 0, stream>>>(X, Hb, ln1_g + i * EMBED, ln1_b + i * EMBED, Ntok);
        mfma_gemm<128><<<dim3(HIDDEN / 128, gy128), 256, 0, stream>>>(
            Hb, fc1_w + (size_t)i * HIDDEN * EMBED, fc1_b + i * HIDDEN, nullptr,
            nullptr, nullptr, Gb, nullptr, nullptr, nullptr,
            M, HIDDEN, EMBED, EMBED, Ntok, SEQMAX, 2, mg);
        // fc2 split-K z=2; partials O + H, residual and reduction fused into
        // ln_sum_f32 (which replaces the old ln2 pass).
        mfma_gemm<64><<<dim3(EMBED / 128, gy64, 2), 256, 0, stream>>>(
            Gb, fc2_w + (size_t)i * EMBED * HIDDEN, fc2_b + i * EMBED, nullptr,
            O, H, nullptr, nullptr, nullptr, nullptr,
            M, EMBED, HIDDEN / 2, HIDDEN, Ntok, SEQMAX, 0, mg);
        ln_sum_f32_kernel<<<M, 256, 0, stream>>>(O, H, X, ln2_g + i * EMBED, ln2_b + i * EMBED, Ntok);
    };

    embed(0);
    embed(1);
    block(0, 392);
    embed(2);
    block(1, 588);
    embed(3);
    block(2, 784);

    ln_kernel<<<NB * SEQMAX, 256, 0, stream>>>(X, H, final_g, final_b, SEQMAX);
    mean_kernel<<<NB, 768, 0, stream>>>(H, MEAN);
    gemm_kernel<<<dim3(EMBED / 64, 1), 256, 0, stream>>>(
        MEAN, head_w1, head_b1, nullptr, HH, NB, EMBED, EMBED, NB, NB, 1);
    gemm_kernel<<<dim3(256 / 64, 1), 256, 0, stream>>>(
        HH, head_w2, head_b2, nullptr, PTCH, NB, 256, EMBED, NB, NB, 0);
    bcast_kernel<<<(NB * IMGSZ * IMGSZ + 255) / 256, 256, 0, stream>>>(PTCH, d_out, flag);
}

// Round 6
// 1098.538 us; speedup vs baseline: 1.0801x; 1.0801x over previous
//
#include <hip/hip_runtime.h>
#include <hip/hip_bf16.h>
#include <math.h>

#define EMBED 768
#define QKVD 2304
#define HEADS 12
#define HD 64
#define HIDDEN 3072
#define NPATCH 196
#define SEQMAX 784
#define NB 8
#define IMGSZ 224
#define GRID 14
#define PATCH 16
#define PSTR 72
#define VROW 832

typedef __hip_bfloat16 bf16;
typedef __attribute__((ext_vector_type(8))) short short8;
typedef __attribute__((ext_vector_type(4))) float f32x4;

__device__ __forceinline__ float b2f(bf16 v) { return __bfloat162float(v); }
__device__ __forceinline__ float geluf(float x) {
    return 0.5f * x * (1.0f + erff(x * 0.70710678118654752f));
}

// async global->LDS, 16B per lane. LDS dest is wave-uniform base + lane*16.
__device__ __forceinline__ void async16(const bf16* g, bf16* l) {
    __builtin_amdgcn_global_load_lds(
        (const __attribute__((address_space(1))) unsigned int*)g,
        (__attribute__((address_space(3))) unsigned int*)l,
        16, 0, 0);
}

#define WAIT_VM0   0x0F70   // vmcnt(0)
#define WAIT_VM3   0x0F73   // vmcnt(3)
#define WAIT_VM4   0x0F74   // vmcnt(4)
#define WAIT_VM5   0x0F75   // vmcnt(5)
#define WAIT_VM6   0x0F76   // vmcnt(6)
#define WAIT_LGKM0 0xC07F   // lgkmcnt(0)

// ---------------------------------------------------------------------------
// Dtype detection (bf16 vs fp32 inputs).
// ---------------------------------------------------------------------------
__global__ __launch_bounds__(256)
void detect_kernel(const unsigned short* __restrict__ raw, int* __restrict__ flag)
{
    __shared__ int bad;
    if (threadIdx.x == 0) bad = 0;
    __syncthreads();
    for (int i = threadIdx.x; i < 8192; i += 256) {
        unsigned int u = (unsigned int)raw[i] << 16;
        float v = __uint_as_float(u);
        if (!(fabsf(v) <= 1e4f)) bad = 1;
    }
    __syncthreads();
    if (threadIdx.x == 0) *flag = bad;
}

// ---------------------------------------------------------------------------
// Fused converters.
// ---------------------------------------------------------------------------
struct CvtF32 {
    const void* src[19];
    int n[19];
    int dstOff[19];
    int blkOff[20];
};
__global__ __launch_bounds__(256)
void convert_f32_all(CvtF32 c, float* __restrict__ base, const int* __restrict__ flag)
{
    int f = *flag;
    int b = blockIdx.x;
    int i = 0;
    #pragma unroll
    for (int j = 0; j < 19; ++j) if (b >= c.blkOff[j + 1]) i = j + 1;
    int e = ((b - c.blkOff[i]) * 256 + threadIdx.x) * 4;
    if (e >= c.n[i]) return;
    float* dst = base + c.dstOff[i] + e;
    if (f) {
        *(float4*)dst = *(const float4*)((const float*)c.src[i] + e);
    } else {
        const bf16* s = (const bf16*)c.src[i] + e;
        dst[0] = b2f(s[0]); dst[1] = b2f(s[1]); dst[2] = b2f(s[2]); dst[3] = b2f(s[3]);
    }
}

struct CvtB16 {
    const void* src[5];
    int n[5];
    int dstOff[5];
    int blkOff[6];
};
__global__ __launch_bounds__(256)
void convert_b16_all(CvtB16 c, bf16* __restrict__ base, const int* __restrict__ flag)
{
    int f = *flag;
    int b = blockIdx.x;
    int i = 0;
    #pragma unroll
    for (int j = 0; j < 5; ++j) if (b >= c.blkOff[j + 1]) i = j + 1;
    int e = ((b - c.blkOff[i]) * 256 + threadIdx.x) * 4;
    if (e >= c.n[i]) return;
    bf16* dst = base + (size_t)c.dstOff[i] + e;
    if (f) {
        float4 v = *(const float4*)((const float*)c.src[i] + e);
        dst[0] = __float2bfloat16(v.x); dst[1] = __float2bfloat16(v.y);
        dst[2] = __float2bfloat16(v.z); dst[3] = __float2bfloat16(v.w);
    } else {
        *(uint2*)dst = *(const uint2*)((const bf16*)c.src[i] + e);
    }
}

// ---------------------------------------------------------------------------
// MFMA bf16 GEMM, templated M-tile (MT x 128), BK=32.
// Staging: A ring-2 (prefetch distance 1; A-tiles L2-hot) + B ring-3
// (distance 2). LDS: MT=64 -> 32 KB, MT=128 -> 40 KB.
// MT=128 (fc1/qkv, large-N): 16 MFMA per barrier window and 0.5 ds_read/MFMA.
// vmcnt schedule (queue-simulated; prologue B0,A0,B1; in-loop stageA(it+1)
// then stageB(it+2)): steady MT=64 vmcnt(5) / MT=128 vmcnt(6), tail 3/4, 0.
// Split-K (gridDim.z==2): partials to outF/outF2, bias on z==0 only,
// reduction fused into the consumer (ln_sum_f32 / posadd).
// Bijective XCD swizzle (m204). LDS col-slot XOR swizzle f(row)=(row>>1)&3
// on 16B slots, applied to GLOBAL source col + read slot (involution):
// bank-conflict-free (round-1: 5.4M -> 0).
// mode: 0 = fp32 out; 1 = fp32 out + residual; 2 = bf16 out + gelu;
//       3 = qkv head-split -> bf16 Q/K/V all [bh][t][64].
// ---------------------------------------------------------------------------
template<int MT>
__global__ __launch_bounds__(256, 4)
void mfma_gemm(const bf16* __restrict__ A, const bf16* __restrict__ W,
               const float* __restrict__ bias, const float* __restrict__ add,
               float* __restrict__ outF, float* __restrict__ outF2,
               bf16* __restrict__ outB,
               bf16* __restrict__ Qb, bf16* __restrict__ Kb, bf16* __restrict__ Vb,
               int M, int N, int K, int kpitch, int Ntok, int rowStride,
               int mode, int magic)
{
    constexpr int MI = MT / 32;            // m-frags per wave (4 or 2)
    __shared__ __align__(16) bf16 As[2][MT * 32];
    __shared__ __align__(16) bf16 Bs[3][128 * 32];
    int tid = threadIdx.x;
    int lane = tid & 63;
    int wave = tid >> 6;
    int wm = wave & 1, wn = wave >> 1;

    // bijective XCD-aware swizzle of the flat workgroup id (m204 form)
    unsigned nx = gridDim.x, ny = gridDim.y;
    unsigned nwg = nx * ny * gridDim.z;
    unsigned orig = blockIdx.x + nx * (blockIdx.y + ny * blockIdx.z);
    unsigned qq = nwg >> 3, rr = nwg & 7;
    unsigned xcd = orig & 7, idx8 = orig >> 3;
    unsigned wg = (xcd < rr ? xcd * (qq + 1) : rr * (qq + 1) + (xcd - rr) * qq) + idx8;
    int bxg = (int)(wg % nx);
    unsigned tmp = wg / nx;
    int byg = (int)(tmp % ny);
    int bzg = (int)(tmp / ny);

    int m0 = byg * MT, n0 = bxg * 128;
    int k0 = bzg * K;

    int lr = lane >> 2;
    int lc = lane & 3;
    int sc = lc ^ ((lr >> 1) & 3);         // swizzled col slot (16B units)
    int ar0 = (MT / 4) * wave + lr;
    int ma0 = m0 + ar0; if (ma0 >= M) ma0 = M - 1;
    int bx0 = (int)(((unsigned)ma0 * (unsigned)magic) >> 24);
    const bf16* aSrc0 = A + (size_t)(bx0 * rowStride + (ma0 - bx0 * Ntok)) * kpitch + k0 + sc * 8;
    const bf16* aSrc1 = nullptr;
    if constexpr (MT == 128) {
        int ma1 = m0 + ar0 + 16; if (ma1 >= M) ma1 = M - 1;
        int bx1 = (int)(((unsigned)ma1 * (unsigned)magic) >> 24);
        aSrc1 = A + (size_t)(bx1 * rowStride + (ma1 - bx1 * Ntok)) * kpitch + k0 + sc * 8;
    }
    const bf16* bSrc0 = W + (size_t)(n0 + 32 * wave + lr) * kpitch + k0 + sc * 8;
    const bf16* bSrc1 = W + (size_t)(n0 + 32 * wave + 16 + lr) * kpitch + k0 + sc * 8;

    int fr = lane & 15;
    int fq = lane >> 4;
    int sq = fq ^ ((fr >> 1) & 3);         // swizzled read slot
    int aOff = (wm * (MT / 2) + fr) * 32 + sq * 8;
    int bOff = (wn * 64 + fr) * 32 + sq * 8;

    f32x4 acc[MI][4] = {};

    auto stageA = [&](int buf) {
        async16(aSrc0, As[buf] + ((MT / 4) * wave) * 32);
        aSrc0 += 32;
        if constexpr (MT == 128) {
            async16(aSrc1, As[buf] + ((MT / 4) * wave + 16) * 32);
            aSrc1 += 32;
        }
    };
    auto stageB = [&](int buf) {
        async16(bSrc0, Bs[buf] + (32 * wave) * 32);
        async16(bSrc1, Bs[buf] + (32 * wave + 16) * 32);
        bSrc0 += 32; bSrc1 += 32;
    };

    int nIter = K >> 5;                 // >= 12 at all call sites
    // prologue issue order matters for the vmcnt counting: B(0), A(0), B(1)
    stageB(0);
    stageA(0);
    stageB(1);

    int cur = 0;                        // Bs ring index (= it % 3); As index = it & 1
    for (int it = 0; it < nIter; ++it) {
        __builtin_amdgcn_sched_barrier(0);
        __builtin_amdgcn_s_waitcnt(WAIT_LGKM0);   // my reads of overwrite targets done
        __builtin_amdgcn_s_barrier();             // all waves done reading them
        if (it + 1 < nIter) stageA((it + 1) & 1);
        if (it + 2 < nIter) {
            int nb = cur + 2; if (nb >= 3) nb -= 3;
            stageB(nb);
            // drain A(it)+B(it); leave B(it+1), A(it+1), B(it+2) in flight
            if constexpr (MT == 128) __builtin_amdgcn_s_waitcnt(WAIT_VM6);
            else                     __builtin_amdgcn_s_waitcnt(WAIT_VM5);
        } else if (it + 1 < nIter) {
            if constexpr (MT == 128) __builtin_amdgcn_s_waitcnt(WAIT_VM4);
            else                     __builtin_amdgcn_s_waitcnt(WAIT_VM3);
        } else {
            __builtin_amdgcn_s_waitcnt(WAIT_VM0);
        }
        __builtin_amdgcn_s_barrier();             // current buffers visible to all waves
        __builtin_amdgcn_sched_barrier(0);

        const bf16* aR = As[it & 1] + aOff;
        const bf16* bR = Bs[cur] + bOff;
        short8 af[MI], bfr[4];
        #pragma unroll
        for (int mi = 0; mi < MI; ++mi) af[mi] = *(const short8*)(aR + mi * 16 * 32);
        #pragma unroll
        for (int ni = 0; ni < 4; ++ni) bfr[ni] = *(const short8*)(bR + ni * 16 * 32);
        #pragma unroll
        for (int mi = 0; mi < MI; ++mi)
            #pragma unroll
            for (int ni = 0; ni < 4; ++ni)
                acc[mi][ni] = __builtin_amdgcn_mfma_f32_16x16x32_bf16(
                    af[mi], bfr[ni], acc[mi][ni], 0, 0, 0);
        if (++cur >= 3) cur = 0;
    }

    // ---- epilogue ----
    float* oF = bzg ? outF2 : outF;
    float bsv[4];
    #pragma unroll
    for (int ni = 0; ni < 4; ++ni)
        bsv[ni] = bzg ? 0.f : bias[n0 + wn * 64 + ni * 16 + fr];

    if (mode == 3) {
        bf16* dstb[4]; int hhv[4], dcv[4];
        #pragma unroll
        for (int ni = 0; ni < 4; ++ni) {
            int nb = n0 + wn * 64 + ni * 16;          // multiple of 16 -> lane-uniform
            int which = (nb >= 1536) ? 2 : (nb >= 768) ? 1 : 0;
            int nnb = nb - which * 768;
            dstb[ni] = (which == 0) ? Qb : (which == 1) ? Kb : Vb;
            hhv[ni] = nnb >> 6;
            dcv[ni] = (nnb & 63) + fr;
        }
        #pragma unroll
        for (int mi = 0; mi < MI; ++mi)
            #pragma unroll
            for (int r = 0; r < 4; ++r) {
                int m = m0 + wm * (MT / 2) + mi * 16 + fq * 4 + r;
                if (m >= M) continue;
                int bx_ = (int)(((unsigned)m * (unsigned)magic) >> 24);
                int t = m - bx_ * Ntok;
                #pragma unroll
                for (int ni = 0; ni < 4; ++ni)
                    dstb[ni][((size_t)(bx_ * HEADS + hhv[ni]) * SEQMAX + t) * HD + dcv[ni]]
                        = __float2bfloat16(acc[mi][ni][r] + bsv[ni]);
            }
    } else {
        #pragma unroll
        for (int mi = 0; mi < MI; ++mi)
            #pragma unroll
            for (int r = 0; r < 4; ++r) {
                int m = m0 + wm * (MT / 2) + mi * 16 + fq * 4 + r;
                if (m >= M) continue;
                int bx_ = (int)(((unsigned)m * (unsigned)magic) >> 24);
                int t = m - bx_ * Ntok;
                size_t rb = (size_t)(bx_ * rowStride + t) * N;
                #pragma unroll
                for (int ni = 0; ni < 4; ++ni) {
                    int n = n0 + wn * 64 + ni * 16 + fr;
                    float v = acc[mi][ni][r] + bsv[ni];
                    if (mode == 0)      oF[rb + n] = v;
                    else if (mode == 1) oF[rb + n] = v + add[rb + n];
                    else                outB[rb + n] = __float2bfloat16(geluf(v));
                }
            }
    }
}

// ---------------------------------------------------------------------------
// Legacy fp32 GEMM (tiny head matmuls only).
// ---------------------------------------------------------------------------
__global__ __launch_bounds__(256)
void gemm_kernel(const float* __restrict__ A, const float* __restrict__ W,
                 const float* __restrict__ bias, const float* __restrict__ add,
                 float* __restrict__ C, int M, int N, int K,
                 int Ntok, int rowStride, int dogelu)
{
    __shared__ __align__(16) float As[16][68];
    __shared__ __align__(16) float Ws[16][68];
    int tid = threadIdx.x;
    int tx = tid & 15, ty = tid >> 4;
    int n0 = blockIdx.x * 64, m0 = blockIdx.y * 64;
    int lrow = tid >> 2;
    int lk   = (tid & 3) << 2;
    int am = m0 + lrow;
    bool aok = (am < M);
    const float* Arow = A;
    if (aok) {
        int pr = (am / Ntok) * rowStride + (am % Ntok);
        Arow = A + (size_t)pr * K;
    }
    int wn = n0 + lrow;
    const float* Wrow = (wn < N) ? (W + (size_t)wn * K) : nullptr;
    float acc[4][4] = {};
    for (int kk = 0; kk < K; kk += 16) {
        float4 av = make_float4(0.f, 0.f, 0.f, 0.f);
        if (aok) av = *(const float4*)(Arow + kk + lk);
        float4 wv = make_float4(0.f, 0.f, 0.f, 0.f);
        if (Wrow) wv = *(const float4*)(Wrow + kk + lk);
        __syncthreads();
        As[lk+0][lrow] = av.x; As[lk+1][lrow] = av.y;
        As[lk+2][lrow] = av.z; As[lk+3][lrow] = av.w;
        Ws[lk+0][lrow] = wv.x; Ws[lk+1][lrow] = wv.y;
        Ws[lk+2][lrow] = wv.z; Ws[lk+3][lrow] = wv.w;
        __syncthreads();
        #pragma unroll
        for (int k = 0; k < 16; ++k) {
            float4 a = *(const float4*)&As[k][ty << 2];
            float4 w = *(const float4*)&Ws[k][tx << 2];
            acc[0][0] += a.x*w.x; acc[0][1] += a.x*w.y; acc[0][2] += a.x*w.z; acc[0][3] += a.x*w.w;
            acc[1][0] += a.y*w.x; acc[1][1] += a.y*w.y; acc[1][2] += a.y*w.z; acc[1][3] += a.y*w.w;
            acc[2][0] += a.z*w.x; acc[2][1] += a.z*w.y; acc[2][2] += a.z*w.z; acc[2][3] += a.z*w.w;
            acc[3][0] += a.w*w.x; acc[3][1] += a.w*w.y; acc[3][2] += a.w*w.z; acc[3][3] += a.w*w.w;
        }
    }
    #pragma unroll
    for (int i = 0; i < 4; ++i) {
        int m = m0 + (ty << 2) + i;
        if (m >= M) continue;
        int pr = (m / Ntok) * rowStride + (m % Ntok);
        float* crow = C + (size_t)pr * N;
        const float* addrow = add ? (add + (size_t)pr * N) : nullptr;
        #pragma unroll
        for (int j = 0; j < 4; ++j) {
            int n = n0 + (tx << 2) + j;
            float v = acc[i][j] + bias[n];
            if (addrow) v += addrow[n];
            if (dogelu) v = geluf(v);
            crow[n] = v;
        }
    }
}

// ---------------------------------------------------------------------------
// LayerNorms.
// ---------------------------------------------------------------------------
__global__ __launch_bounds__(256)
void ln_bf16_kernel(const float* __restrict__ src, bf16* __restrict__ dst,
                    const float* __restrict__ g, const float* __restrict__ bta, int Ntok)
{
    __shared__ float red[256];
    int blk = blockIdx.x;
    int t = blk % Ntok, b = blk / Ntok;
    size_t row = ((size_t)b * SEQMAX + t) * EMBED;
    int tid = threadIdx.x;
    float v0 = src[row + tid], v1 = src[row + tid + 256], v2 = src[row + tid + 512];
    red[tid] = v0 + v1 + v2;
    __syncthreads();
    for (int off = 128; off; off >>= 1) { if (tid < off) red[tid] += red[tid + off]; __syncthreads(); }
    float mu = red[0] * (1.0f / EMBED);
    __syncthreads();
    float d0 = v0 - mu, d1 = v1 - mu, d2 = v2 - mu;
    red[tid] = d0*d0 + d1*d1 + d2*d2;
    __syncthreads();
    for (int off = 128; off; off >>= 1) { if (tid < off) red[tid] += red[tid + off]; __syncthreads(); }
    float rs = rsqrtf(red[0] * (1.0f / EMBED) + 1e-5f);
    dst[row + tid]       = __float2bfloat16(d0 * rs * g[tid]       + bta[tid]);
    dst[row + tid + 256] = __float2bfloat16(d1 * rs * g[tid + 256] + bta[tid + 256]);
    dst[row + tid + 512] = __float2bfloat16(d2 * rs * g[tid + 512] + bta[tid + 512]);
}

__global__ __launch_bounds__(256)
void ln_kernel(const float* __restrict__ src, float* __restrict__ dst,
               const float* __restrict__ g, const float* __restrict__ bta, int Ntok)
{
    __shared__ float red[256];
    int blk = blockIdx.x;
    int t = blk % Ntok, b = blk / Ntok;
    size_t row = ((size_t)b * SEQMAX + t) * EMBED;
    int tid = threadIdx.x;
    float v0 = src[row + tid], v1 = src[row + tid + 256], v2 = src[row + tid + 512];
    red[tid] = v0 + v1 + v2;
    __syncthreads();
    for (int off = 128; off; off >>= 1) { if (tid < off) red[tid] += red[tid + off]; __syncthreads(); }
    float mu = red[0] * (1.0f / EMBED);
    __syncthreads();
    float d0 = v0 - mu, d1 = v1 - mu, d2 = v2 - mu;
    red[tid] = d0*d0 + d1*d1 + d2*d2;
    __syncthreads();
    for (int off = 128; off; off >>= 1) { if (tid < off) red[tid] += red[tid + off]; __syncthreads(); }
    float rs = rsqrtf(red[0] * (1.0f / EMBED) + 1e-5f);
    dst[row + tid]       = d0 * rs * g[tid]       + bta[tid];
    dst[row + tid + 256] = d1 * rs * g[tid + 256] + bta[tid + 256];
    dst[row + tid + 512] = d2 * rs * g[tid + 512] + bta[tid + 512];
}

// Split-K reduction fused into ln2: X = LN(pa + pb + X) (in-place residual).
__global__ __launch_bounds__(256)
void ln_sum_f32_kernel(const float* __restrict__ pa, const float* __restrict__ pb,
                       float* __restrict__ X, const float* __restrict__ g,
                       const float* __restrict__ bta, int Ntok)
{
    __shared__ float red[256];
    int blk = blockIdx.x;
    int t = blk % Ntok, b = blk / Ntok;
    size_t row = ((size_t)b * SEQMAX + t) * EMBED;
    int tid = threadIdx.x;
    float v0 = pa[row + tid]       + pb[row + tid]       + X[row + tid];
    float v1 = pa[row + tid + 256] + pb[row + tid + 256] + X[row + tid + 256];
    float v2 = pa[row + tid + 512] + pb[row + tid + 512] + X[row + tid + 512];
    red[tid] = v0 + v1 + v2;
    __syncthreads();
    for (int off = 128; off; off >>= 1) { if (tid < off) red[tid] += red[tid + off]; __syncthreads(); }
    float mu = red[0] * (1.0f / EMBED);
    __syncthreads();
    float d0 = v0 - mu, d1 = v1 - mu, d2 = v2 - mu;
    red[tid] = d0*d0 + d1*d1 + d2*d2;
    __syncthreads();
    for (int off = 128; off; off >>= 1) { if (tid < off) red[tid] += red[tid + off]; __syncthreads(); }
    float rs = rsqrtf(red[0] * (1.0f / EMBED) + 1e-5f);
    X[row + tid]       = d0 * rs * g[tid]       + bta[tid];
    X[row + tid + 256] = d1 * rs * g[tid + 256] + bta[tid + 256];
    X[row + tid + 512] = d2 * rs * g[tid + 512] + bta[tid + 512];
}

// ---------------------------------------------------------------------------
// V transpose: V [bh][t][64] -> VT [bh*64+d][VROW], zero-padded keys>=Ntok.
// XCD-pinned decode: same bh -> same XCD as flash (bh = (flat&7)*12 + j%12),
// so VT is produced into the L2 that flash will read it from.
// ---------------------------------------------------------------------------
__global__ __launch_bounds__(256)
void vtrans_kernel(const bf16* __restrict__ Vh, bf16* __restrict__ VT, int Ntok)
{
    __shared__ unsigned short Lt[64 * 66];
    unsigned o = blockIdx.x + gridDim.x * blockIdx.y;   // grid (96, nkt)
    unsigned x = o & 7, j = o >> 3;
    int bh = (int)(x * 12 + j % 12);
    int k0 = (int)(j / 12) * 64;
    const bf16* Vb = Vh + (size_t)bh * SEQMAX * HD;
    int tid = threadIdx.x;
    #pragma unroll
    for (int pass = 0; pass < 8; ++pass) {
        int key_l = (tid >> 5) + pass * 8;
        int d2 = tid & 31;
        unsigned v = 0;
        if (k0 + key_l < Ntok)
            v = *(const unsigned*)(Vb + (size_t)(k0 + key_l) * HD + d2 * 2);
        *(unsigned*)&Lt[key_l * 66 + 2 * d2] = v;
    }
    __syncthreads();
    #pragma unroll
    for (int pass = 0; pass < 8; ++pass) {
        int d = (tid >> 5) + pass * 8;
        int kp = tid & 31;
        unsigned lo = Lt[(2 * kp) * 66 + d];
        unsigned hi = Lt[(2 * kp + 1) * 66 + d];
        *(unsigned*)(VT + ((size_t)bh * HD + d) * VROW + k0 + 2 * kp) = lo | (hi << 16);
    }
}

// ---------------------------------------------------------------------------
// MFMA flash attention v6 — GEMM-structure transplant.
// r2-r4 evidence: flash@784 = 80us invariant under prefetch depth, register
// cuts, z-split, XCD pinning -> the invariant suspect is the load structure
// (every wave privately re-loading the same K/V tile from global: 64 dwordx4
// per block per k-tile, serially exposed). This version copies the PROVEN
// mfma_gemm structure: K/V tiles staged to LDS via global_load_lds (async16),
// shared by all 4 waves (16 async16/block/tile), double-buffered, counted
// vmcnt (stage(next) -> vmcnt(4) -> barrier; tail vmcnt(0)).
// LDS XOR swizzle: 8x16B slots per 128B row; store side pre-swizzles the
// GLOBAL source slot ((l&7)^(l>>3) since async16 writes linearly), read side
// applies slot^(row&7) -> worst 2-way conflict (free, m136).
// z-split reverted (r3/r4: +30us regression): direct bf16 Ob write.
// Fused softmax (r4) and XCD-pinned bh decode retained.
// LDS: 2x8KB K + 2x8KB V + 18KB P = 50KB -> 3 blocks/CU (12 waves/CU vs 5.6).
// ---------------------------------------------------------------------------
__global__ __launch_bounds__(256)
void flash_mfma(const bf16* __restrict__ Qh, const bf16* __restrict__ Kh,
                const bf16* __restrict__ VT, bf16* __restrict__ O, int Ntok)
{
    __shared__ __align__(16) bf16 Ks[2][64 * 64];
    __shared__ __align__(16) bf16 Vs[2][64 * 64];
    __shared__ __align__(16) unsigned short Plds[4][32 * PSTR];

    // XCD-pinned bijective decode: grid (96, nqt), nwg multiple of 8.
    unsigned o = blockIdx.x + gridDim.x * blockIdx.y;
    unsigned x = o & 7, j = o >> 3;
    int bh = (int)(x * 12 + j % 12);
    int t0 = (int)(j / 12) * 128;

    int b = bh / HEADS, h = bh % HEADS;
    int tid = threadIdx.x;
    int lane = tid & 63, w = tid >> 6;
    int fr = lane & 15, fq = lane >> 4;

    const bf16* Qb = Qh + (size_t)bh * SEQMAX * HD;
    const bf16* Kb = Kh + (size_t)bh * SEQMAX * HD;
    const bf16* Vt = VT + (size_t)bh * HD * VROW;

    short8 aq[2][2];
    #pragma unroll
    for (int qi = 0; qi < 2; ++qi) {
        int tq = t0 + w * 32 + qi * 16 + fr; if (tq >= Ntok) tq = Ntok - 1;
        aq[qi][0] = *(const short8*)(Qb + (size_t)tq * HD + fq * 8);
        aq[qi][1] = *(const short8*)(Qb + (size_t)tq * HD + fq * 8 + 32);
    }

    float lpart[2][4] = {};
    f32x4 oacc[2][4];
    #pragma unroll
    for (int qi = 0; qi < 2; ++qi)
        #pragma unroll
        for (int dg = 0; dg < 4; ++dg) oacc[qi][dg] = (f32x4){0.f, 0.f, 0.f, 0.f};

    unsigned short* Pw = Plds[w];

    // staging geometry: wave w owns tile rows [16w,16w+16) in 2 chunks of 8.
    // async16 writes linearly (lane l -> row base+ (l>>3), slot l&7); the
    // XOR swizzle slot^=(row&7) is therefore applied on the GLOBAL src slot.
    int srow = lane >> 3;                   // 0..7 within chunk
    int sslot = (lane & 7) ^ srow;          // pre-swizzled 16B source slot
    int ntile = (Ntok + 63) >> 6;

    auto stage = [&](int buf, int kt) {
        int kk = kt * 64;
        #pragma unroll
        for (int c = 0; c < 2; ++c) {
            int row = 16 * w + c * 8 + srow;
            int key = kk + row; if (key >= Ntok) key = Ntok - 1;   // clamp; masked in softmax
            async16(Kb + (size_t)key * HD + sslot * 8, Ks[buf] + (16 * w + c * 8) * 64);
            async16(Vt + (size_t)row * VROW + kk + sslot * 8, Vs[buf] + (16 * w + c * 8) * 64);
        }
    };

    stage(0, 0);                            // 4 async16 outstanding

    int rs = fr & 7;                        // row&7 for fragment rows kg*16+fr
    for (int kt = 0; kt < ntile; ++kt) {
        int cur = kt & 1;
        int k0 = kt * 64;
        __builtin_amdgcn_sched_barrier(0);
        __builtin_amdgcn_s_waitcnt(WAIT_LGKM0);  // my LDS reads of overwrite target done
        __builtin_amdgcn_s_barrier();            // all waves done with buffer cur^1
        if (kt + 1 < ntile) {
            stage(cur ^ 1, kt + 1);              // 8 outstanding
            __builtin_amdgcn_s_waitcnt(WAIT_VM4);  // drain cur's 4, keep next's 4
        } else {
            __builtin_amdgcn_s_waitcnt(WAIT_VM0);
        }
        __builtin_amdgcn_s_barrier();            // buffer cur visible to all waves
        __builtin_amdgcn_sched_barrier(0);

        const bf16* Kc = Ks[cur];
        const bf16* Vc = Vs[cur];

        // QK + fused softmax per kg (S consumed immediately)
        #pragma unroll
        for (int kg = 0; kg < 4; ++kg) {
            short8 bk0 = *(const short8*)(Kc + (kg * 16 + fr) * 64 + (fq ^ rs) * 8);
            short8 bk1 = *(const short8*)(Kc + (kg * 16 + fr) * 64 + ((fq + 4) ^ rs) * 8);
            bool ok = (k0 + kg * 16 + fr) < Ntok;
            #pragma unroll
            for (int qi = 0; qi < 2; ++qi) {
                f32x4 sa = (f32x4){0.f, 0.f, 0.f, 0.f};
                sa = __builtin_amdgcn_mfma_f32_16x16x32_bf16(aq[qi][0], bk0, sa, 0, 0, 0);
                sa = __builtin_amdgcn_mfma_f32_16x16x32_bf16(aq[qi][1], bk1, sa, 0, 0, 0);
                #pragma unroll
                for (int r = 0; r < 4; ++r) {
                    float p = ok ? __expf(fminf(sa[r] * 0.125f, 80.f)) : 0.f;
                    lpart[qi][r] += p;
                    bf16 pb = __float2bfloat16(p);
                    Pw[(qi * 16 + fq * 4 + r) * PSTR + kg * 16 + fr] = *(unsigned short*)&pb;
                }
            }
        }

        short8 ap[2][2];
        #pragma unroll
        for (int qi = 0; qi < 2; ++qi) {
            ap[qi][0] = *(const short8*)(Pw + (qi * 16 + fr) * PSTR + fq * 8);
            ap[qi][1] = *(const short8*)(Pw + (qi * 16 + fr) * PSTR + fq * 8 + 32);
        }

        #pragma unroll
        for (int dg = 0; dg < 4; ++dg) {
            short8 bv0 = *(const short8*)(Vc + (dg * 16 + fr) * 64 + (fq ^ rs) * 8);
            short8 bv1 = *(const short8*)(Vc + (dg * 16 + fr) * 64 + ((fq + 4) ^ rs) * 8);
            #pragma unroll
            for (int qi = 0; qi < 2; ++qi) {
                oacc[qi][dg] = __builtin_amdgcn_mfma_f32_16x16x32_bf16(
                    ap[qi][0], bv0, oacc[qi][dg], 0, 0, 0);
                oacc[qi][dg] = __builtin_amdgcn_mfma_f32_16x16x32_bf16(
                    ap[qi][1], bv1, oacc[qi][dg], 0, 0, 0);
            }
        }
    }

    // epilogue: normalize (max-free softmax denominator) and write bf16 Ob.
    #pragma unroll
    for (int qi = 0; qi < 2; ++qi)
        #pragma unroll
        for (int r = 0; r < 4; ++r) {
            float l = lpart[qi][r];
            l += __shfl_xor(l, 1); l += __shfl_xor(l, 2);
            l += __shfl_xor(l, 4); l += __shfl_xor(l, 8);
            int t = t0 + w * 32 + qi * 16 + fq * 4 + r;
            if (t >= Ntok) continue;
            float inv = 1.0f / l;
            bf16* dst = O + ((size_t)b * SEQMAX + t) * EMBED + h * HD;
            #pragma unroll
            for (int dg = 0; dg < 4; ++dg)
                dst[dg * 16 + fr] = __float2bfloat16(oacc[qi][dg][r] * inv);
        }
}

// ---------------------------------------------------------------------------
__global__ __launch_bounds__(256)
void patch_gather(const void* __restrict__ img, bf16* __restrict__ Ap,
                  const int* __restrict__ flag)
{
    int f = *flag;
    int idx = blockIdx.x * 256 + threadIdx.x;
    if (idx >= NB * NPATCH * EMBED) return;
    int col = idx % EMBED;
    int row = idx / EMBED;
    int t = row % NPATCH, b = row / NPATCH;
    int c = col >> 8;
    int pr = (col >> 4) & 15;
    int pc = col & 15;
    int gr = t / GRID, gc = t % GRID;
    size_t off = ((size_t)(b * 3 + c) * IMGSZ + gr * PATCH + pr) * IMGSZ + gc * PATCH + pc;
    float v = f ? ((const float*)img)[off] : b2f(((const bf16*)img)[off]);
    Ap[idx] = __float2bfloat16(v);
}

__global__ __launch_bounds__(256)
void posadd_kernel(const float* __restrict__ PEO, const float* __restrict__ PEO2,
                   const float* __restrict__ sp, const float* __restrict__ ip,
                   float* __restrict__ X, int imgIdx)
{
    int idx = blockIdx.x * 256 + threadIdx.x;
    if (idx >= NB * NPATCH * EMBED) return;
    int e = idx % EMBED;
    int row = idx / EMBED;
    int t = row % NPATCH, b = row / NPATCH;
    float pos = (e < 384) ? sp[t * 384 + e] : ip[imgIdx * 384 + (e - 384)];
    X[((size_t)b * SEQMAX + imgIdx * NPATCH + t) * EMBED + e] = PEO[idx] + PEO2[idx] + pos;
}

__global__ __launch_bounds__(768)
void mean_kernel(const float* __restrict__ H, float* __restrict__ Mn)
{
    int b = blockIdx.x;
    int e = threadIdx.x;
    float s = 0.f;
    for (int t = 0; t < SEQMAX; ++t) s += H[((size_t)b * SEQMAX + t) * EMBED + e];
    Mn[b * EMBED + e] = s * (1.0f / SEQMAX);
}

__global__ __launch_bounds__(256)
void bcast_kernel(const float* __restrict__ P, void* __restrict__ out,
                  const int* __restrict__ flag)
{
    int f = *flag;
    int idx = blockIdx.x * 256 + threadIdx.x;
    if (idx >= NB * IMGSZ * IMGSZ) return;
    int c = idx % IMGSZ;
    int r = (idx / IMGSZ) % IMGSZ;
    int b = idx / (IMGSZ * IMGSZ);
    float v = P[b * 256 + (r & 15) * 16 + (c & 15)];
    if (f) ((float*)out)[idx] = v;
    else   ((bf16*)out)[idx] = __float2bfloat16(v);
}

// ---------------------------------------------------------------------------
extern "C" void kernel_launch(void* const* d_in, const int* in_sizes, int n_in,
                              void* d_out, int out_size, void* d_ws, size_t ws_size,
                              hipStream_t stream)
{
    (void)n_in; (void)out_size; (void)ws_size;
    const void* img[4] = {d_in[0], d_in[1], d_in[2], d_in[3]};

    float* ws = (float*)d_ws;
    int* flag = (int*)ws;

    detect_kernel<<<1, 256, 0, stream>>>((const unsigned short*)d_in[0], flag);

    const bool isBig[28] = {0,0,0,0, 1,0,0,0, 0,0,1,0, 1,0,0,0, 1,0,1,0, 0,0,0,0, 0,0,0,0};
    float* fBase = ws + 16;
    float* fPtr[28] = {};
    CvtF32 cf;
    int fCnt = 0, fBlk = 0;
    cf.blkOff[0] = 0;
    {
        float* p = fBase;
        for (int i = 4; i < 28; ++i) {
            if (isBig[i]) continue;
            fPtr[i] = p;
            int n = in_sizes[i];
            cf.src[fCnt] = d_in[i];
            cf.n[fCnt] = n;
            cf.dstOff[fCnt] = (int)(p - fBase);
            fBlk += (n + 1023) / 1024;
            cf.blkOff[fCnt + 1] = fBlk;
            p += n;
            ++fCnt;
        }
        fBase = ws + 16;
        fPtr[0] = p;   // sentinel: arena end
    }
    convert_f32_all<<<fBlk, 256, 0, stream>>>(cf, fBase, flag);

    bf16* bPtr[28] = {};
    bf16* bBase = (bf16*)fPtr[0];
    CvtB16 cb;
    int bCnt = 0, bBlk = 0;
    cb.blkOff[0] = 0;
    float* arenaEnd;
    {
        bf16* p = bBase;
        for (int i = 4; i < 28; ++i) {
            if (!isBig[i]) continue;
            bPtr[i] = p;
            int n = in_sizes[i];
            cb.src[bCnt] = d_in[i];
            cb.n[bCnt] = n;
            cb.dstOff[bCnt] = (int)(p - bBase);
            bBlk += (n + 1023) / 1024;
            cb.blkOff[bCnt + 1] = bBlk;
            p += n;
            ++bCnt;
        }
        size_t off = p - (bf16*)ws;
        off = (off + 7) & ~(size_t)7;
        arenaEnd = (float*)((bf16*)ws + off);
    }
    convert_b16_all<<<bBlk, 256, 0, stream>>>(cb, bBase, flag);

    const bf16* pe_w   = bPtr[4];
    const bf16* qkv_w  = bPtr[10];
    const bf16* proj_w = bPtr[12];
    const bf16* fc1_w  = bPtr[16];
    const bf16* fc2_w  = bPtr[18];
    const float* pe_b      = fPtr[5];
    const float* sp        = fPtr[6];
    const float* ip        = fPtr[7];
    const float* ln_attn_g = fPtr[8];
    const float* ln_attn_b = fPtr[9];
    const float* qkv_b     = fPtr[11];
    const float* proj_b    = fPtr[13];
    const float* ln1_g     = fPtr[14];
    const float* ln1_b     = fPtr[15];
    const float* fc1_b     = fPtr[17];
    const float* fc2_b     = fPtr[19];
    const float* ln2_g     = fPtr[20];
    const float* ln2_b     = fPtr[21];
    const float* final_g   = fPtr[22];
    const float* final_b   = fPtr[23];
    const float* head_w1   = fPtr[24];
    const float* head_b1   = fPtr[25];
    const float* head_w2   = fPtr[26];
    const float* head_b2   = fPtr[27];

    const size_t SEQ = (size_t)NB * SEQMAX * EMBED;          // 4,816,896
    const size_t HID_ELEMS = (size_t)NB * SEQMAX * HIDDEN;   // 19,267,584
    const size_t EMB_ELEMS = (size_t)NB * NPATCH * EMBED;    // 1,204,224
    float* X    = arenaEnd;
    float* H    = X + SEQ;
    float* O    = H + SEQ;
    float* PEO  = O + SEQ;
    float* MEAN = PEO + EMB_ELEMS;
    float* HH   = MEAN + NB * EMBED;
    float* PTCH = HH + NB * EMBED;
    bf16* Hb    = (bf16*)(PTCH + NB * 256 + 16);
    bf16* Ob    = Hb + SEQ;
    bf16* Gb    = Ob + SEQ;
    bf16* PEb   = Gb + HID_ELEMS;
    bf16* Qb    = PEb + EMB_ELEMS;
    bf16* Kb    = Qb + SEQ;
    bf16* Vb    = Kb + SEQ;
    bf16* VTb   = Vb + SEQ;

    const int nEmb = NB * NPATCH * EMBED;

    // magic for unsigned division by d via (m*magic)>>24; valid for the q<=7,
    // d in {392,588,784,1568} cases used here ((q+1)*e < magic holds).
    auto magicOf = [](int d) { return (int)(16777216u / (unsigned)d + 1u); };
    const int mgE = magicOf(NB * NPATCH);

    auto embed = [&](int i) {
        patch_gather<<<(nEmb + 255) / 256, 256, 0, stream>>>(img[i], PEb, flag);
        // split-K z=2 (grid was 150 blocks -> badly grid-starved); partials
        // PEO + H (H is free scratch at embed time), summed in posadd.
        dim3 g(EMBED / 128, (NB * NPATCH + 63) / 64, 2);
        mfma_gemm<64><<<g, 256, 0, stream>>>(PEb, pe_w + (size_t)i * EMBED * EMBED,
                                             pe_b + i * EMBED, nullptr, PEO, H, nullptr,
                                             nullptr, nullptr, nullptr,
                                             NB * NPATCH, EMBED, EMBED / 2, EMBED,
                                             NB * NPATCH, NB * NPATCH, 0, mgE);
        posadd_kernel<<<(nEmb + 255) / 256, 256, 0, stream>>>(PEO, H, sp, ip, X, i);
    };

    auto block = [&](int i, int Ntok) {
        int M = NB * Ntok;
        int gy64  = (M + 63) / 64;
        int gy128 = (M + 127) / 128;
        int nkt = (Ntok + 63) / 64;
        int nqt = (Ntok + 127) / 128;
        int mg = magicOf(Ntok);
        ln_bf16_kernel<<<M, 256, 0, stream>>>(X, Hb, ln_attn_g + i * EMBED, ln_attn_b + i * EMBED, Ntok);
        mfma_gemm<128><<<dim3(QKVD / 128, gy128), 256, 0, stream>>>(
            Hb, qkv_w + (size_t)i * QKVD * EMBED, qkv_b + i * QKVD, nullptr,
            nullptr, nullptr, nullptr, Qb, Kb, Vb, M, QKVD, EMBED, EMBED,
            Ntok, SEQMAX, 3, mg);
        vtrans_kernel<<<dim3(96, nkt), 256, 0, stream>>>(Vb, VTb, Ntok);
        // LDS-staged flash (GEMM-structure), direct bf16 Ob write, no split.
        flash_mfma<<<dim3(96, nqt), 256, 0, stream>>>(Qb, Kb, VTb, Ob, Ntok);
        mfma_gemm<64><<<dim3(EMBED / 128, gy64), 256, 0, stream>>>(
            Ob, proj_w + (size_t)i * EMBED * EMBED, proj_b + i * EMBED, X,
            X, nullptr, nullptr, nullptr, nullptr, nullptr,
            M, EMBED, EMBED, EMBED, Ntok, SEQMAX, 1, mg);
        ln_bf16_kernel<<<M, 256, 0, stream>>>(X, Hb, ln1_g + i * EMBED, ln1_b + i * EMBED, Ntok);
        mfma_gemm<128><<<dim3(HIDDEN / 128, gy128), 256, 0, stream>>>(
            Hb, fc1_w + (size_t)i * HIDDEN * EMBED, fc1_b + i * HIDDEN, nullptr,
            nullptr, nullptr, Gb, nullptr, nullptr, nullptr,
            M, HIDDEN, EMBED, EMBED, Ntok, SEQMAX, 2, mg);
        // fc2 split-K z=2; partials O + H, residual and reduction fused into
        // ln_sum_f32 (which replaces the old ln2 pass).
        mfma_gemm<64><<<dim3(EMBED / 128, gy64, 2), 256, 0, stream>>>(
            Gb, fc2_w + (size_t)i * EMBED * HIDDEN, fc2_b + i * EMBED, nullptr,
            O, H, nullptr, nullptr, nullptr, nullptr,
            M, EMBED, HIDDEN / 2, HIDDEN, Ntok, SEQMAX, 0, mg);
        ln_sum_f32_kernel<<<M, 256, 0, stream>>>(O, H, X, ln2_g + i * EMBED, ln2_b + i * EMBED, Ntok);
    };

    embed(0);
    embed(1);
    block(0, 392);
    embed(2);
    block(1, 588);
    embed(3);
    block(2, 784);

    ln_kernel<<<NB * SEQMAX, 256, 0, stream>>>(X, H, final_g, final_b, SEQMAX);
    mean_kernel<<<NB, 768, 0, stream>>>(H, MEAN);
    gemm_kernel<<<dim3(EMBED / 64, 1), 256, 0, stream>>>(
        MEAN, head_w1, head_b1, nullptr, HH, NB, EMBED, EMBED, NB, NB, 1);
    gemm_kernel<<<dim3(256 / 64, 1), 256, 0, stream>>>(
        HH, head_w2, head_b2, nullptr, PTCH, NB, 256, EMBED, NB, NB, 0);
    bcast_kernel<<<(NB * IMGSZ * IMGSZ + 255) / 256, 256, 0, stream>>>(PTCH, d_out, flag);
}